// Round 3
// baseline (38254.712 us; speedup 1.0000x reference)
//
#include <hip/hip_runtime.h>
#include <hip/hip_bf16.h>

#define SB 64      // batch
#define SS 512     // seq len
#define SI 256     // input dim
#define SH 1024    // hidden dim
#define SO 256     // output dim
#define NL 3       // layers

#define PBLK 256   // persistent grid (1 block/CU nominal; capacity >= 2/CU guaranteed)
#define PTHR 256

typedef __attribute__((ext_vector_type(8))) short bf16x8;
typedef __attribute__((ext_vector_type(4))) float f32x4;

__device__ __forceinline__ unsigned short f2bf(float f) {
  unsigned int u = __float_as_uint(f);
  u += 0x7fff + ((u >> 16) & 1);   // RNE
  return (unsigned short)(u >> 16);
}

// ---------------- prologue kernels ----------------

// src: (K, N) fp32 row-major  ->  dst: (N, K) bf16 row-major
__global__ void k_transpose(const float* __restrict__ src, unsigned short* __restrict__ dst,
                            int K, int N) {
  __shared__ float tile[32][33];
  int n0 = blockIdx.x * 32, k0 = blockIdx.y * 32;
  int tx = threadIdx.x & 31, ty = threadIdx.x >> 5;  // 32 x 8
  for (int i = ty; i < 32; i += 8)
    tile[i][tx] = src[(size_t)(k0 + i) * N + (n0 + tx)];
  __syncthreads();
  for (int i = ty; i < 32; i += 8)
    dst[(size_t)(n0 + i) * K + (k0 + tx)] = f2bf(tile[tx][i]);
}

// h0: (B, L, H) -> h_f32/h_bf: (L, B, H)
__global__ void k_init_h(const float* __restrict__ h0, float* __restrict__ h_f32,
                         unsigned short* __restrict__ h_bf) {
  int idx = blockIdx.x * blockDim.x + threadIdx.x;
  if (idx >= NL * SB * SH) return;
  int l = idx >> 16; int rem = idx & 65535; int b = rem >> 10; int c = rem & 1023;
  float v = h0[((size_t)b * NL + l) * SH + c];
  h_f32[idx] = v;
  h_bf[idx] = f2bf(v);
}

// ---------------- GEMM helper ----------------
// Wave computes a 16(M) x 16(N) tile; A: (M,K) row-major bf16, B: (N,K) row-major bf16 (B^T).
template<int K>
__device__ __forceinline__ void gemm_k(const unsigned short* __restrict__ Ap,
                                       const unsigned short* __restrict__ Bp,
                                       f32x4& acc0, f32x4& acc1) {
#pragma unroll 4
  for (int k0 = 0; k0 < K; k0 += 64) {
    bf16x8 a0 = *(const bf16x8*)(Ap + k0);
    bf16x8 b0 = *(const bf16x8*)(Bp + k0);
    bf16x8 a1 = *(const bf16x8*)(Ap + k0 + 32);
    bf16x8 b1 = *(const bf16x8*)(Bp + k0 + 32);
    acc0 = __builtin_amdgcn_mfma_f32_16x16x32_bf16(a0, b0, acc0, 0, 0, 0);
    acc1 = __builtin_amdgcn_mfma_f32_16x16x32_bf16(a1, b1, acc1, 0, 0, 0);
  }
}

// ---------------- persistent kernel ----------------

struct GruArgs {
  const float* x;
  const unsigned short* Wx0t;
  const unsigned short* Wx1t;
  const unsigned short* Wx2t;
  const unsigned short* Wh0t;
  const unsigned short* Wh1t;
  const unsigned short* Wh2t;
  const unsigned short* Wyt;
  const float* bh0;
  const float* bhx;   // (2, 3H)
  const float* by;
  unsigned short* h_bf;     // (3,B,H)
  unsigned short* rh_bf;    // (3,B,H)
  float* h_f32;             // (3,B,H)
  float* z_f32;             // (3,B,H)
  float* gxg_f32;           // (3,B,H)
  float* out;
  unsigned* bar;            // [0]=arrive, [32]=release (128B apart)
};

// grid barrier: monotone epoch, agent-scope atomics, deadlock-free since all
// PBLK=256 blocks fit (launch_bounds caps VGPR at 256 -> >=2 blocks/CU capacity).
__device__ __forceinline__ void gbar(unsigned* arrive, unsigned* release, unsigned epoch) {
  __syncthreads();
  if (threadIdx.x == 0) {
    __threadfence();   // release: flush prior writes to coherence point
    unsigned prev = __hip_atomic_fetch_add(arrive, 1u, __ATOMIC_ACQ_REL,
                                           __HIP_MEMORY_SCOPE_AGENT);
    if (prev == epoch * PBLK + (PBLK - 1))
      __hip_atomic_store(release, epoch + 1u, __ATOMIC_RELEASE,
                         __HIP_MEMORY_SCOPE_AGENT);
    while (__hip_atomic_load(release, __ATOMIC_RELAXED,
                             __HIP_MEMORY_SCOPE_AGENT) < epoch + 1u)
      __builtin_amdgcn_s_sleep(2);
    __threadfence();   // acquire: invalidate caches before reading peers' data
  }
  __syncthreads();
}

__device__ __forceinline__ void do_tileA(const GruArgs& A, int ta, int s,
                                         int row0, int lrow, int kg) {
  f32x4 acc0 = {0.f, 0.f, 0.f, 0.f};
  f32x4 acc1 = {0.f, 0.f, 0.f, 0.f};
  if (ta < 576) {
    const int l  = ta / 192;
    const int c0 = (ta % 192) << 4;
    const int t  = s - l;
    if (t < 0 || t >= SS) return;
    const int col = c0 + lrow;
    const unsigned short* Wxt = (l == 0) ? A.Wx0t : ((l == 1) ? A.Wx1t : A.Wx2t);
    const unsigned short* Wht = (l == 0) ? A.Wh0t : ((l == 1) ? A.Wh1t : A.Wh2t);
    const float* bias = (l == 0) ? A.bh0 : (A.bhx + (size_t)(l - 1) * 3 * SH);

    if (l == 0) {
      // x-side GEMM, K = SI, fp32 -> bf16 in-register
      const float* Ax = A.x + ((size_t)(row0 + lrow) * SS + t) * SI + kg * 8;
      const unsigned short* Bp = Wxt + (size_t)col * SI + kg * 8;
#pragma unroll
      for (int k0 = 0; k0 < SI; k0 += 64) {
        bf16x8 a0, a1;
        const float* A0 = Ax + k0;
        const float* A1 = Ax + k0 + 32;
#pragma unroll
        for (int q = 0; q < 8; ++q) {
          a0[q] = (short)f2bf(A0[q]);
          a1[q] = (short)f2bf(A1[q]);
        }
        bf16x8 b0 = *(const bf16x8*)(Bp + k0);
        bf16x8 b1 = *(const bf16x8*)(Bp + k0 + 32);
        acc0 = __builtin_amdgcn_mfma_f32_16x16x32_bf16(a0, b0, acc0, 0, 0, 0);
        acc1 = __builtin_amdgcn_mfma_f32_16x16x32_bf16(a1, b1, acc1, 0, 0, 0);
      }
    } else {
      const unsigned short* curh = A.h_bf + (size_t)(l - 1) * SB * SH;
      gemm_k<SH>(curh + (size_t)(row0 + lrow) * SH + kg * 8,
                 Wxt + (size_t)col * SH + kg * 8, acc0, acc1);
    }

    if (c0 < 2 * SH) {
      const unsigned short* hb = A.h_bf + (size_t)l * SB * SH;
      gemm_k<SH>(hb + (size_t)(row0 + lrow) * SH + kg * 8,
                 Wht + (size_t)col * SH + kg * 8, acc0, acc1);
      const float bsum = bias[col];
      const float* hf = A.h_f32 + (size_t)l * SB * SH;
#pragma unroll
      for (int j = 0; j < 4; ++j) {
        const int row = row0 + kg * 4 + j;
        const float v = acc0[j] + acc1[j] + bsum;
        const float sg = 1.f / (1.f + __expf(-v));
        if (col < SH) {
          A.z_f32[((size_t)l * SB + row) * SH + col] = sg;
        } else {
          const int cg = col - SH;
          const float hp = hf[(size_t)row * SH + cg];
          A.rh_bf[((size_t)l * SB + row) * SH + cg] = f2bf(sg * hp);
        }
      }
    } else {
      const int cg = col - 2 * SH;
#pragma unroll
      for (int j = 0; j < 4; ++j) {
        const int row = row0 + kg * 4 + j;
        A.gxg_f32[((size_t)l * SB + row) * SH + cg] = acc0[j] + acc1[j];
      }
    }
  } else {
    // y projection for t = s - 3 using h_bf[2] (holds h2(s-3))
    const int ty = s - 3;
    if (ty < 0 || ty >= SS) return;
    const int c0  = (ta - 576) << 4;
    const int col = c0 + lrow;
    const unsigned short* h2 = A.h_bf + (size_t)2 * SB * SH;
    gemm_k<SH>(h2 + (size_t)(row0 + lrow) * SH + kg * 8,
               A.Wyt + (size_t)col * SH + kg * 8, acc0, acc1);
    const float bsum = A.by[col];
#pragma unroll
    for (int j = 0; j < 4; ++j) {
      const int row = row0 + kg * 4 + j;
      A.out[((size_t)row * SS + ty) * SO + col] = acc0[j] + acc1[j] + bsum;
    }
  }
}

__device__ __forceinline__ void do_tileB(const GruArgs& A, int tb, int s,
                                         int row0, int lrow, int kg) {
  const int lb  = tb >> 6;
  const int cb0 = (tb & 63) << 4;
  const int t   = s - lb;
  if (t < 0 || t >= SS) return;
  const unsigned short* Wht = (lb == 0) ? A.Wh0t : ((lb == 1) ? A.Wh1t : A.Wh2t);
  const float* bias = (lb == 0) ? A.bh0 : (A.bhx + (size_t)(lb - 1) * 3 * SH);
  const int col = cb0 + lrow;

  f32x4 acc0 = {0.f, 0.f, 0.f, 0.f};
  f32x4 acc1 = {0.f, 0.f, 0.f, 0.f};
  const unsigned short* rh = A.rh_bf + (size_t)lb * SB * SH;
  gemm_k<SH>(rh + (size_t)(row0 + lrow) * SH + kg * 8,
             Wht + ((size_t)(2 * SH + col)) * SH + kg * 8, acc0, acc1);

  const float bsum = bias[2 * SH + col];
#pragma unroll
  for (int j = 0; j < 4; ++j) {
    const int row = row0 + kg * 4 + j;
    const size_t idx = ((size_t)lb * SB + row) * SH + col;
    float v = acc0[j] + acc1[j] + A.gxg_f32[idx] + bsum;
    float e = __expf(2.f * v);
    float g = 1.f - 2.f / (e + 1.f);   // tanh(v)
    float z = A.z_f32[idx];
    float hp = A.h_f32[idx];
    float hn = z * hp + (1.f - z) * g;
    A.h_f32[idx] = hn;
    A.h_bf[idx] = f2bf(hn);
  }
}

__global__ __launch_bounds__(PTHR, 2) void k_gru(GruArgs A) {
  const int tid  = threadIdx.x;
  const int wid  = tid >> 6;
  const int lane = tid & 63;
  const int lrow = lane & 15;
  const int kg   = lane >> 4;
  const int row0 = wid << 4;
  const int blk  = blockIdx.x;
  unsigned* arrive  = A.bar;
  unsigned* release = A.bar + 32;

  // ---- cost-balanced phase-A tile assignment (592 tiles over 256 blocks) ----
  // classes: A=l0-zr(1280) ta 0..127 | B=l0-g(256) 128..191 | C=zr(2048)
  // 192..319,384..511 | D=g/y(1024) 320..383,512..591
  int t0, t1, t2 = -1;
  if (blk < 64)        { t0 = 192 + blk; t1 = 128 + blk; t2 = 320 + blk; }          // C+B+D
  else if (blk < 80)   { int i = blk - 64; t0 = 256 + i; t1 = 512 + 2 * i; t2 = 513 + 2 * i; } // C+D+D
  else if (blk < 128)  { int j = blk - 80; t0 = 272 + j; t1 = (j < 32) ? 544 + j : 576 + (j - 32); } // C+D
  else                 { int m = blk - 128; t0 = 384 + m; t1 = m; }                 // C+A

  unsigned epoch = 0;
  for (int s = 0; s <= SS + 2; ++s) {
    do_tileA(A, t0, s, row0, lrow, kg);
    do_tileA(A, t1, s, row0, lrow, kg);
    if (t2 >= 0) do_tileA(A, t2, s, row0, lrow, kg);
    gbar(arrive, release, epoch++);
    if (blk < 192) do_tileB(A, blk, s, row0, lrow, kg);
    gbar(arrive, release, epoch++);
  }

  // epilogue: final hidden state -> out tail
  for (int idx = blk * PTHR + tid; idx < NL * SB * SH; idx += PBLK * PTHR) {
    int l2 = idx >> 16; int rem = idx & 65535; int b = rem >> 10; int c = rem & 1023;
    A.out[(size_t)SB * SS * SO + ((size_t)b * NL + l2) * SH + c] = A.h_f32[idx];
  }
}

// ---------------- launcher ----------------
extern "C" void kernel_launch(void* const* d_in, const int* in_sizes, int n_in,
                              void* d_out, int out_size, void* d_ws, size_t ws_size,
                              hipStream_t stream) {
  (void)in_sizes; (void)n_in; (void)out_size; (void)ws_size;
  const float* x   = (const float*)d_in[0];
  const float* h0  = (const float*)d_in[1];
  const float* Wx0 = (const float*)d_in[2];
  const float* Wh0 = (const float*)d_in[3];
  const float* bh0 = (const float*)d_in[4];
  const float* Wx  = (const float*)d_in[5];
  const float* Wh  = (const float*)d_in[6];
  const float* bh  = (const float*)d_in[7];
  const float* Wy  = (const float*)d_in[8];
  const float* by  = (const float*)d_in[9];
  float* out = (float*)d_out;

  char* p = (char*)d_ws;
  auto take = [&](size_t bytes) {
    char* r = p;
    p += (bytes + 255) & ~(size_t)255;
    return r;
  };
  unsigned short* Wx0t = (unsigned short*)take((size_t)3 * SH * SI * 2);
  unsigned short* Wx1t = (unsigned short*)take((size_t)3 * SH * SH * 2);
  unsigned short* Wx2t = (unsigned short*)take((size_t)3 * SH * SH * 2);
  unsigned short* Wh0t = (unsigned short*)take((size_t)3 * SH * SH * 2);
  unsigned short* Wh1t = (unsigned short*)take((size_t)3 * SH * SH * 2);
  unsigned short* Wh2t = (unsigned short*)take((size_t)3 * SH * SH * 2);
  unsigned short* Wyt  = (unsigned short*)take((size_t)SO * SH * 2);
  unsigned short* h_bf = (unsigned short*)take((size_t)NL * SB * SH * 2);
  unsigned short* rh_bf = (unsigned short*)take((size_t)NL * SB * SH * 2);
  float* h_f32   = (float*)take((size_t)NL * SB * SH * 4);
  float* z_f32   = (float*)take((size_t)NL * SB * SH * 4);
  float* gxg_f32 = (float*)take((size_t)NL * SB * SH * 4);
  unsigned* bar  = (unsigned*)take(256);

  hipMemsetAsync(bar, 0, 256, stream);

  // weight transposition + bf16 conversion (N x K layout, B^T convention)
  k_transpose<<<dim3(3 * SH / 32, SI / 32), 256, 0, stream>>>(Wx0, Wx0t, SI, 3 * SH);
  k_transpose<<<dim3(3 * SH / 32, SH / 32), 256, 0, stream>>>(Wx, Wx1t, SH, 3 * SH);
  k_transpose<<<dim3(3 * SH / 32, SH / 32), 256, 0, stream>>>(Wx + (size_t)SH * 3 * SH, Wx2t, SH, 3 * SH);
  k_transpose<<<dim3(3 * SH / 32, SH / 32), 256, 0, stream>>>(Wh0, Wh0t, SH, 3 * SH);
  k_transpose<<<dim3(3 * SH / 32, SH / 32), 256, 0, stream>>>(Wh, Wh1t, SH, 3 * SH);
  k_transpose<<<dim3(3 * SH / 32, SH / 32), 256, 0, stream>>>(Wh + (size_t)SH * 3 * SH, Wh2t, SH, 3 * SH);
  k_transpose<<<dim3(SO / 32, SH / 32), 256, 0, stream>>>(Wy, Wyt, SH, SO);
  k_init_h<<<(NL * SB * SH) / 256, 256, 0, stream>>>(h0, h_f32, h_bf);

  GruArgs args;
  args.x = x;
  args.Wx0t = Wx0t; args.Wx1t = Wx1t; args.Wx2t = Wx2t;
  args.Wh0t = Wh0t; args.Wh1t = Wh1t; args.Wh2t = Wh2t;
  args.Wyt = Wyt;
  args.bh0 = bh0; args.bhx = bh; args.by = by;
  args.h_bf = h_bf; args.rh_bf = rh_bf;
  args.h_f32 = h_f32; args.z_f32 = z_f32; args.gxg_f32 = gxg_f32;
  args.out = out;
  args.bar = bar;

  k_gru<<<PBLK, PTHR, 0, stream>>>(args);
}

// Round 4
// 22671.513 us; speedup vs baseline: 1.6873x; 1.6873x over previous
//
#include <hip/hip_runtime.h>
#include <hip/hip_bf16.h>

#define SB 64      // batch
#define SS 512     // seq len
#define SI 256     // input dim
#define SH 1024    // hidden dim
#define SO 256     // output dim
#define NL 3       // layers

#define NBLK 208   // 192 gate blocks (3 layers x 64 col-tiles) + 16 y blocks
#define DYN_LDS 131072

typedef __attribute__((ext_vector_type(8))) short bf16x8;
typedef __attribute__((ext_vector_type(4))) float f32x4;

__device__ __forceinline__ unsigned short f2bf(float f) {
  unsigned int u = __float_as_uint(f);
  u += 0x7fff + ((u >> 16) & 1);   // RNE
  return (unsigned short)(u >> 16);
}

__device__ __forceinline__ f32x4 MF(bf16x8 a, bf16x8 b, f32x4 c) {
  return __builtin_amdgcn_mfma_f32_16x16x32_bf16(a, b, c, 0, 0, 0);
}

// ---------------- prologue kernels ----------------

// src: (K, N) fp32 row-major  ->  dst: (N, K) bf16 row-major
__global__ void k_transpose(const float* __restrict__ src, unsigned short* __restrict__ dst,
                            int K, int N) {
  __shared__ float tile[32][33];
  int n0 = blockIdx.x * 32, k0 = blockIdx.y * 32;
  int tx = threadIdx.x & 31, ty = threadIdx.x >> 5;  // 32 x 8
  for (int i = ty; i < 32; i += 8)
    tile[i][tx] = src[(size_t)(k0 + i) * N + (n0 + tx)];
  __syncthreads();
  for (int i = ty; i < 32; i += 8)
    dst[(size_t)(n0 + i) * K + (k0 + tx)] = f2bf(tile[tx][i]);
}

// h0: (B, L, H) -> h_bf: (L, B, H)
__global__ void k_init_h(const float* __restrict__ h0, unsigned short* __restrict__ h_bf) {
  int idx = blockIdx.x * blockDim.x + threadIdx.x;
  if (idx >= NL * SB * SH) return;
  int l = idx >> 16; int rem = idx & 65535; int b = rem >> 10; int c = rem & 1023;
  h_bf[idx] = f2bf(h0[((size_t)b * NL + l) * SH + c]);
}

// ---------------- persistent kernel ----------------

struct GruArgs {
  const float* x;
  const float* h0;
  const unsigned short* Wx0t;
  const unsigned short* Wx1t;
  const unsigned short* Wx2t;
  const unsigned short* Wh0t;
  const unsigned short* Wh1t;
  const unsigned short* Wh2t;
  const unsigned short* Wyt;
  const float* bh0;
  const float* bhx;   // (2, 3H)
  const float* by;
  unsigned short* h_bf;     // (3,B,H)
  unsigned short* rh_bf;    // (3,B,H)
  float* out;
  unsigned* flags;          // [NBLK] arrive flags (monotone epochs)
  unsigned* rel;            // release word (separate cacheline)
};

extern __shared__ char sm[];

// copy a 16-col x K weight tile (contiguous 'bytes' at src) into LDS with
// XOR bank swizzle: byte ^= ((col & 7) << 4); col = byte_off >> CS.
template<int CS>
__device__ __forceinline__ void stage_tile(char* dst, const char* src, int bytes, int tid) {
  for (int o = tid * 16; o < bytes; o += 4096) {
    int4 v = *(const int4*)(src + o);
    int ph = o ^ ((o >> (CS - 4)) & 0x70);
    *(int4*)(dst + ph) = v;
  }
}

// store-flag grid barrier: 1 device-scope store per block; block0/wave0 polls.
__device__ __forceinline__ void gbar(unsigned* flags, unsigned* rel, unsigned e,
                                     int blk, int tid) {
  __syncthreads();                       // drains vmcnt for all waves
  if (tid == 0) {
    __threadfence();                     // wbl2: push rh/h stores to coherence point
    __hip_atomic_store(&flags[blk], e + 1, __ATOMIC_RELEASE, __HIP_MEMORY_SCOPE_AGENT);
  }
  if (blk == 0 && tid < 64) {
    for (;;) {
      bool ok = true;
      for (int i = tid; i < NBLK; i += 64)
        ok &= (__hip_atomic_load(&flags[i], __ATOMIC_RELAXED,
                                 __HIP_MEMORY_SCOPE_AGENT) >= e + 1);
      if (__all(ok)) break;
      __builtin_amdgcn_s_sleep(1);
    }
    if (tid == 0)
      __hip_atomic_store(rel, e + 1, __ATOMIC_RELEASE, __HIP_MEMORY_SCOPE_AGENT);
  }
  if (tid == 0) {
    while (__hip_atomic_load(rel, __ATOMIC_RELAXED, __HIP_MEMORY_SCOPE_AGENT) < e + 1)
      __builtin_amdgcn_s_sleep(1);
    __threadfence();                     // inv: L1/L2 invalidate before reading peers
  }
  __syncthreads();
}

__global__ __launch_bounds__(256, 1) void k_gru(GruArgs A) {
  const int tid  = threadIdx.x;
  const int lane = tid & 63;
  const int wid  = tid >> 6;
  const int lrow = lane & 15;
  const int kg   = lane >> 4;
  const int kb   = kg * 8;
  const int row0 = wid << 4;
  const int blk  = blockIdx.x;
  const int swzm = (lrow & 7) << 4;      // per-lane LDS XOR mask

  const bool isY = (blk >= 192);
  const int  l   = isY ? -1 : (blk >> 6);
  const int  c0  = isY ? ((blk - 192) << 4) : ((blk & 63) << 4);
  const int  colg = c0 + lrow;

  // ---- stage weights into LDS (once) ----
  if (!isY) {
    const unsigned short* WhT = (l == 0) ? A.Wh0t : ((l == 1) ? A.Wh1t : A.Wh2t);
    for (int g = 0; g < 3; ++g)    // whz | whr | whg at 0 / 32K / 64K
      stage_tile<11>(sm + g * 32768, (const char*)(WhT + (size_t)(g * SH + c0) * SH),
                     32768, tid);
    if (l == 0) {                  // all of Wx0 fits: 3 x 8KB at 96K..120K
      for (int g = 0; g < 3; ++g)
        stage_tile<9>(sm + 98304 + g * 8192,
                      (const char*)(A.Wx0t + (size_t)(g * SH + c0) * SI), 8192, tid);
    } else {                       // wxz at 96K; wxr/wxg streamed from global
      const unsigned short* WxT = (l == 1) ? A.Wx1t : A.Wx2t;
      stage_tile<11>(sm + 98304, (const char*)(WxT + (size_t)c0 * SH), 32768, tid);
    }
  } else {
    stage_tile<11>(sm, (const char*)(A.Wyt + (size_t)c0 * SH), 32768, tid);
  }

  // ---- per-lane bias + register-resident h state ----
  float bz = 0.f, br = 0.f, bg = 0.f;
  f32x4 hreg = {0.f, 0.f, 0.f, 0.f};
  if (!isY) {
    const float* bias = (l == 0) ? A.bh0 : (A.bhx + (size_t)(l - 1) * 3 * SH);
    bz = bias[colg]; br = bias[SH + colg]; bg = bias[2 * SH + colg];
#pragma unroll
    for (int j = 0; j < 4; ++j)
      hreg[j] = A.h0[((size_t)(row0 + kg * 4 + j) * NL + l) * SH + colg];
  } else {
    bg = A.by[colg];
  }
  __syncthreads();

  const int lb1 = lrow * 2048 + kb * 2;   // K=1024 tile logical byte offset
  const int lb0 = lrow * 512 + kb * 2;    // K=256 tile

  unsigned e = 0;
  for (int s = 0; s <= SS + 2; ++s) {
    f32x4 accz = {0.f,0.f,0.f,0.f}, accr = {0.f,0.f,0.f,0.f}, accg = {0.f,0.f,0.f,0.f};
    const int t = isY ? (s - 3) : (s - l);
    const bool act = (t >= 0 && t < SS);

    // ================= phase A =================
    if (act) {
      if (isY) {
        const unsigned short* hp = A.h_bf + (size_t)2 * SB * SH
                                   + (size_t)(row0 + lrow) * SH + kb;
#pragma unroll 4
        for (int k0 = 0; k0 < SH; k0 += 32) {
          bf16x8 a = *(const bf16x8*)(hp + k0);
          bf16x8 w = *(const bf16x8*)(sm + ((lb1 + k0 * 2) ^ swzm));
          accg = MF(a, w, accg);
        }
#pragma unroll
        for (int j = 0; j < 4; ++j)
          A.out[((size_t)(row0 + kg * 4 + j) * SS + t) * SO + colg] = accg[j] + bg;
      } else if (l == 0) {
        // x-side GEMM, K=256, all weights in LDS
        const float* xp = A.x + ((size_t)(row0 + lrow) * SS + t) * SI + kb;
#pragma unroll
        for (int k0 = 0; k0 < SI; k0 += 32) {
          bf16x8 a;
          const float* ap = xp + k0;
#pragma unroll
          for (int q = 0; q < 8; ++q) a[q] = (short)f2bf(ap[q]);
          const int lo = (lb0 + k0 * 2) ^ swzm;
          accz = MF(a, *(const bf16x8*)(sm + 98304 + lo), accz);
          accr = MF(a, *(const bf16x8*)(sm + 106496 + lo), accr);
          accg = MF(a, *(const bf16x8*)(sm + 114688 + lo), accg);
        }
        // h-side zr GEMM, K=1024
        const unsigned short* hp = A.h_bf + (size_t)(row0 + lrow) * SH + kb;
#pragma unroll 4
        for (int k0 = 0; k0 < SH; k0 += 32) {
          bf16x8 a = *(const bf16x8*)(hp + k0);
          const int lo = (lb1 + k0 * 2) ^ swzm;
          accz = MF(a, *(const bf16x8*)(sm + lo), accz);
          accr = MF(a, *(const bf16x8*)(sm + 32768 + lo), accr);
        }
      } else {
        const unsigned short* a1p = A.h_bf + (size_t)(l - 1) * SB * SH
                                    + (size_t)(row0 + lrow) * SH + kb;
        const unsigned short* a2p = A.h_bf + (size_t)l * SB * SH
                                    + (size_t)(row0 + lrow) * SH + kb;
        const unsigned short* WxT = (l == 1) ? A.Wx1t : A.Wx2t;
        const unsigned short* wrp = WxT + (size_t)(SH + colg) * SH + kb;
        const unsigned short* wgp = WxT + (size_t)(2 * SH + colg) * SH + kb;
#pragma unroll 4
        for (int k0 = 0; k0 < SH; k0 += 32) {
          bf16x8 a1 = *(const bf16x8*)(a1p + k0);
          bf16x8 a2 = *(const bf16x8*)(a2p + k0);
          bf16x8 wrv = *(const bf16x8*)(wrp + k0);
          bf16x8 wgv = *(const bf16x8*)(wgp + k0);
          const int lo = (lb1 + k0 * 2) ^ swzm;
          accz = MF(a1, *(const bf16x8*)(sm + 98304 + lo), accz);   // wxz (LDS)
          accz = MF(a2, *(const bf16x8*)(sm + lo), accz);           // whz
          accr = MF(a1, wrv, accr);                                 // wxr (glob)
          accr = MF(a2, *(const bf16x8*)(sm + 32768 + lo), accr);   // whr
          accg = MF(a1, wgv, accg);                                 // wxg (glob)
        }
      }
      if (!isY) {
        unsigned short* rhp = A.rh_bf + (size_t)l * SB * SH;
#pragma unroll
        for (int j = 0; j < 4; ++j) {
          const int row = row0 + kg * 4 + j;
          float zv = 1.f / (1.f + __expf(-(accz[j] + bz)));
          float rv = 1.f / (1.f + __expf(-(accr[j] + br)));
          accz[j] = zv;                                   // keep z for phase B
          rhp[(size_t)row * SH + colg] = f2bf(rv * hreg[j]);
        }
      }
    }

    gbar(A.flags, A.rel, e++, blk, tid);

    // ================= phase B =================
    if (!isY && act) {
      const unsigned short* rp = A.rh_bf + (size_t)l * SB * SH
                                 + (size_t)(row0 + lrow) * SH + kb;
#pragma unroll 4
      for (int k0 = 0; k0 < SH; k0 += 32) {
        bf16x8 a = *(const bf16x8*)(rp + k0);
        bf16x8 w = *(const bf16x8*)(sm + 65536 + ((lb1 + k0 * 2) ^ swzm));  // whg
        accg = MF(a, w, accg);
      }
      unsigned short* hbp = A.h_bf + (size_t)l * SB * SH;
#pragma unroll
      for (int j = 0; j < 4; ++j) {
        const int row = row0 + kg * 4 + j;
        float v = accg[j] + bg;
        float ee = __expf(2.f * v);
        float g = 1.f - 2.f / (ee + 1.f);                 // tanh(v)
        float hn = accz[j] * hreg[j] + (1.f - accz[j]) * g;
        hreg[j] = hn;
        hbp[(size_t)row * SH + colg] = f2bf(hn);
      }
    }

    gbar(A.flags, A.rel, e++, blk, tid);
  }

  // ---- epilogue: register h state -> out tail ----
  if (!isY) {
#pragma unroll
    for (int j = 0; j < 4; ++j)
      A.out[(size_t)SB * SS * SO + ((size_t)(row0 + kg * 4 + j) * NL + l) * SH + colg]
          = hreg[j];
  }
}

// ---------------- launcher ----------------
extern "C" void kernel_launch(void* const* d_in, const int* in_sizes, int n_in,
                              void* d_out, int out_size, void* d_ws, size_t ws_size,
                              hipStream_t stream) {
  (void)in_sizes; (void)n_in; (void)out_size; (void)ws_size;
  const float* x   = (const float*)d_in[0];
  const float* h0  = (const float*)d_in[1];
  const float* Wx0 = (const float*)d_in[2];
  const float* Wh0 = (const float*)d_in[3];
  const float* bh0 = (const float*)d_in[4];
  const float* Wx  = (const float*)d_in[5];
  const float* Wh  = (const float*)d_in[6];
  const float* bh  = (const float*)d_in[7];
  const float* Wy  = (const float*)d_in[8];
  const float* by  = (const float*)d_in[9];
  float* out = (float*)d_out;

  char* p = (char*)d_ws;
  auto take = [&](size_t bytes) {
    char* r = p;
    p += (bytes + 255) & ~(size_t)255;
    return r;
  };
  unsigned short* Wx0t = (unsigned short*)take((size_t)3 * SH * SI * 2);
  unsigned short* Wx1t = (unsigned short*)take((size_t)3 * SH * SH * 2);
  unsigned short* Wx2t = (unsigned short*)take((size_t)3 * SH * SH * 2);
  unsigned short* Wh0t = (unsigned short*)take((size_t)3 * SH * SH * 2);
  unsigned short* Wh1t = (unsigned short*)take((size_t)3 * SH * SH * 2);
  unsigned short* Wh2t = (unsigned short*)take((size_t)3 * SH * SH * 2);
  unsigned short* Wyt  = (unsigned short*)take((size_t)SO * SH * 2);
  unsigned short* h_bf = (unsigned short*)take((size_t)NL * SB * SH * 2);
  unsigned short* rh_bf = (unsigned short*)take((size_t)NL * SB * SH * 2);
  unsigned* bar = (unsigned*)take(1024);

  hipMemsetAsync(bar, 0, 1024, stream);

  k_transpose<<<dim3(3 * SH / 32, SI / 32), 256, 0, stream>>>(Wx0, Wx0t, SI, 3 * SH);
  k_transpose<<<dim3(3 * SH / 32, SH / 32), 256, 0, stream>>>(Wx, Wx1t, SH, 3 * SH);
  k_transpose<<<dim3(3 * SH / 32, SH / 32), 256, 0, stream>>>(Wx + (size_t)SH * 3 * SH, Wx2t, SH, 3 * SH);
  k_transpose<<<dim3(3 * SH / 32, SH / 32), 256, 0, stream>>>(Wh0, Wh0t, SH, 3 * SH);
  k_transpose<<<dim3(3 * SH / 32, SH / 32), 256, 0, stream>>>(Wh, Wh1t, SH, 3 * SH);
  k_transpose<<<dim3(3 * SH / 32, SH / 32), 256, 0, stream>>>(Wh + (size_t)SH * 3 * SH, Wh2t, SH, 3 * SH);
  k_transpose<<<dim3(SO / 32, SH / 32), 256, 0, stream>>>(Wy, Wyt, SH, SO);
  k_init_h<<<(NL * SB * SH) / 256, 256, 0, stream>>>(h0, h_bf);

  GruArgs args;
  args.x = x; args.h0 = h0;
  args.Wx0t = Wx0t; args.Wx1t = Wx1t; args.Wx2t = Wx2t;
  args.Wh0t = Wh0t; args.Wh1t = Wh1t; args.Wh2t = Wh2t;
  args.Wyt = Wyt;
  args.bh0 = bh0; args.bhx = bh; args.by = by;
  args.h_bf = h_bf; args.rh_bf = rh_bf;
  args.out = out;
  args.flags = bar;
  args.rel   = (unsigned*)((char*)bar + 896);

  static bool attr_done = false;
  if (!attr_done) {
    hipFuncSetAttribute((const void*)k_gru,
                        hipFuncAttributeMaxDynamicSharedMemorySize, DYN_LDS);
    attr_done = true;
  }
  k_gru<<<NBLK, 256, DYN_LDS, stream>>>(args);
}